// Round 6
// baseline (573.054 us; speedup 1.0000x reference)
//
#include <hip/hip_runtime.h>
#include <stdint.h>

// ---------- types & helpers ----------
typedef short bf16x8 __attribute__((ext_vector_type(8)));
typedef float f32x4 __attribute__((ext_vector_type(4)));
typedef float f32x16 __attribute__((ext_vector_type(16)));

__device__ __forceinline__ float bf2f(uint16_t u) {
    union { uint32_t i; float f; } c; c.i = ((uint32_t)u) << 16; return c.f;
}
__device__ __forceinline__ uint16_t f2bf(float f) {
    union { float f; uint32_t i; } c; c.f = f;
    uint32_t x = c.i;
    return (uint16_t)((x + 0x7fffu + ((x >> 16) & 1u)) >> 16);  // RNE
}
// truncating pack: (bf16(hi)<<16)|bf16(lo) — OK for all-positive P
__device__ __forceinline__ uint32_t pack2t(float lo, float hi) {
    union { float f; uint32_t u; } a, b;
    a.f = lo; b.f = hi;
    return __builtin_amdgcn_perm(b.u, a.u, 0x07060302u);
}

// raw v_exp_f32 (2^x) — skips OCML denormal-range fixup; scores are bounded
__device__ __forceinline__ float exp2r(float x) {
#if __has_builtin(__builtin_amdgcn_exp2f)
    return __builtin_amdgcn_exp2f(x);
#else
    return exp2f(x);
#endif
}

// v_permlane32_swap_b32:
// post: a[l<32]=a_old[l], a[l>=32]=b_old[l-32];  b[l<32]=a_old[l+32], b[l>=32]=b_old[l]
__device__ __forceinline__ void plane32_swap(uint32_t& a, uint32_t& b) {
#if __has_builtin(__builtin_amdgcn_permlane32_swap)
    typedef unsigned int u32x2 __attribute__((ext_vector_type(2)));
    u32x2 r = __builtin_amdgcn_permlane32_swap(a, b, false, false);
    a = r[0]; b = r[1];
#else
    asm volatile("v_permlane32_swap_b32 %0, %1" : "+v"(a), "+v"(b));
#endif
}

// async global->LDS, 16B per lane; LDS dest = wave-uniform base + lane*16
__device__ __forceinline__ void load_lds16(const void* g, void* lds) {
    using gp_t = const __attribute__((address_space(1))) uint32_t*;
    using lp_t = __attribute__((address_space(3))) uint32_t*;
    __builtin_amdgcn_global_load_lds(
        reinterpret_cast<gp_t>(reinterpret_cast<uintptr_t>(g)),
        reinterpret_cast<lp_t>((uint32_t)reinterpret_cast<uintptr_t>(lds)),
        16, 0, 0);
}

// ---------- single-launch fp32 -> bf16 convert for all inputs ----------
__global__ __launch_bounds__(256) void cvt_all(
    const float* __restrict__ X,
    const float* __restrict__ wqf, const float* __restrict__ wkf,
    const float* __restrict__ wvf, const float* __restrict__ wof,
    const float* __restrict__ w1f, const float* __restrict__ w2f,
    const float* __restrict__ bqf, const float* __restrict__ bkf,
    const float* __restrict__ bvf, const float* __restrict__ bof,
    const float* __restrict__ b1f, const float* __restrict__ b2f,
    uint16_t* __restrict__ Xb, uint16_t* __restrict__ wd, uint16_t* __restrict__ bd)
{
    const int b = blockIdx.x, tid = threadIdx.x;
    const size_t M = 1048576ull;
    const float* s; uint16_t* d; size_t i, off;
    if (b < 8192) {
        i = ((size_t)b * 256 + tid) * 4;
        s = X; off = i; d = Xb;
    } else if (b < 20480) {
        i = ((size_t)(b - 8192) * 256 + tid) * 4;
        d = wd;
        if (i < M)           { s = wqf; off = i; }
        else if (i < 2 * M)  { s = wkf; off = i - M; }
        else if (i < 3 * M)  { s = wvf; off = i - 2 * M; }
        else if (i < 4 * M)  { s = wof; off = i - 3 * M; }
        else if (i < 8 * M)  { s = w1f; off = i - 4 * M; }
        else                 { s = w2f; off = i - 8 * M; }
    } else {
        int j = tid * 4;
        d = bd;
        for (int p = 0; p < 9; ++p, j += 1024) {
            const float* sb; int ob;
            if (j < 1024)      { sb = bqf; ob = j; }
            else if (j < 2048) { sb = bkf; ob = j - 1024; }
            else if (j < 3072) { sb = bvf; ob = j - 2048; }
            else if (j < 4096) { sb = bof; ob = j - 3072; }
            else if (j < 8192) { sb = b1f; ob = j - 4096; }
            else               { sb = b2f; ob = j - 8192; }
            float4 x = *(const float4*)(sb + ob);
            ushort4 u;
            u.x = f2bf(x.x); u.y = f2bf(x.y); u.z = f2bf(x.z); u.w = f2bf(x.w);
            *(ushort4*)(d + j) = u;
        }
        return;
    }
    float4 x = *(const float4*)(s + off);
    ushort4 u;
    u.x = f2bf(x.x); u.y = f2bf(x.y); u.z = f2bf(x.z); u.w = f2bf(x.w);
    *(ushort4*)(d + i) = u;
}

// ---------- generic bf16 GEMM (m97-class 128xNT) ----------
template<int MODE, int NT>
__global__ __launch_bounds__(256) void gemm_bt(
    const uint16_t* __restrict__ A, const uint16_t* __restrict__ B,
    const uint16_t* __restrict__ bias, uint16_t* __restrict__ C,
    int K, int N, int relu)
{
    const int CT = NT / 32;
    __shared__ uint16_t sA[128 * 64];
    __shared__ uint16_t sB[NT * 64];
    const int tid = threadIdx.x;
    const int w = tid >> 6, ln = tid & 63;
    const int m = ln & 15, q = ln >> 4;
    const int wr = w >> 1, wc = w & 1;
    const int tm = blockIdx.y * 128, tn = blockIdx.x * NT;

    f32x4 zero = {0.f, 0.f, 0.f, 0.f};
    f32x4 acc[4][CT];
#pragma unroll
    for (int i = 0; i < 4; ++i)
#pragma unroll
        for (int j = 0; j < CT; ++j) acc[i][j] = zero;

    const int sr = tid >> 3;
    const int sc_ = tid & 7;
    const int g = sc_ ^ (sr & 7);

    for (int k0 = 0; k0 < K; k0 += 64) {
        __syncthreads();
#pragma unroll
        for (int i = 0; i < 4; ++i) {
            int r = i * 32 + sr;
            load_lds16(A + (size_t)(tm + r) * K + k0 + g * 8, &sA[(i * 32 + w * 8) * 64]);
        }
#pragma unroll
        for (int i = 0; i < NT / 32; ++i) {
            int r = i * 32 + sr;
            load_lds16(B + (size_t)(tn + r) * K + k0 + g * 8, &sB[(i * 32 + w * 8) * 64]);
        }
        __syncthreads();
#pragma unroll
        for (int kk = 0; kk < 2; ++kk) {
            bf16x8 af[4], bfr[CT];
            const int s = (kk * 4 + q) ^ (m & 7);
#pragma unroll
            for (int rt = 0; rt < 4; ++rt) {
                int R = wr * 64 + rt * 16 + m;
                af[rt] = *(const bf16x8*)&sA[R * 64 + s * 8];
            }
#pragma unroll
            for (int ct = 0; ct < CT; ++ct) {
                int R = wc * (NT / 2) + ct * 16 + m;
                bfr[ct] = *(const bf16x8*)&sB[R * 64 + s * 8];
            }
#pragma unroll
            for (int rt = 0; rt < 4; ++rt)
#pragma unroll
                for (int ct = 0; ct < CT; ++ct)
                    acc[rt][ct] = __builtin_amdgcn_mfma_f32_16x16x32_bf16(
                        af[rt], bfr[ct], acc[rt][ct], 0, 0, 0);
        }
    }

#pragma unroll
    for (int ct = 0; ct < CT; ++ct) {
        int col = tn + wc * (NT / 2) + ct * 16 + m;
        float bv = bf2f(bias[col]);
#pragma unroll
        for (int rt = 0; rt < 4; ++rt) {
            int rowb = tm + wr * 64 + rt * 16 + q * 4;
#pragma unroll
            for (int rg = 0; rg < 4; ++rg) {
                int t = rowb + rg;
                float v = acc[rt][ct][rg] + bv;
                if (relu) v = fmaxf(v, 0.f);
                C[(size_t)t * N + col] = f2bf(v);
            }
        }
    }
}

// ---------- 256x128 8-wave GEMM, triple-buffered counted-vmcnt pipeline ----------
// (kept for QKV only — measured faster there; W1/W2 revert to gemm_bt)
template<int MODE>
__global__ __launch_bounds__(512, 2) void gemm8(
    const uint16_t* __restrict__ A, const uint16_t* __restrict__ B,
    const uint16_t* __restrict__ bias, uint16_t* __restrict__ C,
    int K, int N, int NBX, int relu)
{
    extern __shared__ uint16_t smem[];

    const int tid = threadIdx.x;
    const int w = tid >> 6, ln = tid & 63;
    const int m = ln & 15, q = ln >> 4;
    const int wr = w >> 1, wc = w & 1;

    const int nwg = gridDim.x;
    const int bid = blockIdx.x;
    const int wg = (bid & 7) * (nwg >> 3) + (bid >> 3);
    const int bx = wg % NBX, by = wg / NBX;
    const int tm = by * 256, tn = bx * 128;

    const int sr = tid >> 3;
    const int g = (tid & 7) ^ (sr & 7);
    const int wbase = w * 512;
    const int KT = K >> 6;

    f32x4 acc[4][4];
#pragma unroll
    for (int i = 0; i < 4; ++i)
#pragma unroll
        for (int j = 0; j < 4; ++j) acc[i][j] = f32x4{0.f, 0.f, 0.f, 0.f};

    auto stageA2 = [&](int buf, int t, int i0) {
        uint16_t* dA = smem + buf * 24576;
#pragma unroll
        for (int i = i0; i < i0 + 2; ++i)
            load_lds16(A + (size_t)(tm + i * 64 + sr) * K + t * 64 + g * 8,
                       dA + i * 4096 + wbase);
    };
    auto stageB1 = [&](int buf, int t, int i) {
        uint16_t* dB = smem + buf * 24576 + 16384;
        load_lds16(B + (size_t)(tn + i * 64 + sr) * K + t * 64 + g * 8,
                   dB + i * 4096 + wbase);
    };

    stageA2(0, 0, 0); stageA2(0, 0, 2); stageB1(0, 0, 0); stageB1(0, 0, 1);
    stageA2(1, 1, 0); stageA2(1, 1, 2); stageB1(1, 1, 0); stageB1(1, 1, 1);
    asm volatile("s_waitcnt vmcnt(6)" ::: "memory");
    __builtin_amdgcn_s_barrier();

    int bufc = 0;
    for (int t = 0; t < KT; ++t) {
        const uint16_t* pA = smem + bufc * 24576;
        const uint16_t* pB = pA + 16384;
        int bufn = bufc + 2; if (bufn >= 3) bufn -= 3;
        const bool pf = (t + 2 < KT);

        bf16x8 af[4], bfr[4];

        {
            const int s = q ^ (m & 7);
#pragma unroll
            for (int mf = 0; mf < 4; ++mf)
                af[mf] = *(const bf16x8*)&pA[(wr * 64 + mf * 16 + m) * 64 + s * 8];
#pragma unroll
            for (int nf = 0; nf < 4; ++nf)
                bfr[nf] = *(const bf16x8*)&pB[(wc * 64 + nf * 16 + m) * 64 + s * 8];
        }
        if (pf) { stageA2(bufn, t + 2, 0); stageB1(bufn, t + 2, 0); }
        __builtin_amdgcn_s_barrier();
        asm volatile("s_waitcnt lgkmcnt(0)" ::: "memory");
        __builtin_amdgcn_sched_barrier(0);
        __builtin_amdgcn_s_setprio(1);
#pragma unroll
        for (int mf = 0; mf < 4; ++mf)
#pragma unroll
            for (int nf = 0; nf < 4; ++nf)
                acc[mf][nf] = __builtin_amdgcn_mfma_f32_16x16x32_bf16(
                    af[mf], bfr[nf], acc[mf][nf], 0, 0, 0);
        __builtin_amdgcn_s_setprio(0);
        __builtin_amdgcn_s_barrier();

        {
            const int s = (4 + q) ^ (m & 7);
#pragma unroll
            for (int mf = 0; mf < 4; ++mf)
                af[mf] = *(const bf16x8*)&pA[(wr * 64 + mf * 16 + m) * 64 + s * 8];
#pragma unroll
            for (int nf = 0; nf < 4; ++nf)
                bfr[nf] = *(const bf16x8*)&pB[(wc * 64 + nf * 16 + m) * 64 + s * 8];
        }
        if (pf) { stageA2(bufn, t + 2, 2); stageB1(bufn, t + 2, 1); }
        __builtin_amdgcn_s_barrier();
        asm volatile("s_waitcnt lgkmcnt(0)" ::: "memory");
        __builtin_amdgcn_sched_barrier(0);
        __builtin_amdgcn_s_setprio(1);
#pragma unroll
        for (int mf = 0; mf < 4; ++mf)
#pragma unroll
            for (int nf = 0; nf < 4; ++nf)
                acc[mf][nf] = __builtin_amdgcn_mfma_f32_16x16x32_bf16(
                    af[mf], bfr[nf], acc[mf][nf], 0, 0, 0);
        __builtin_amdgcn_s_setprio(0);
        if (t + 1 < KT) {
            if (pf) asm volatile("s_waitcnt vmcnt(6)" ::: "memory");
            else    asm volatile("s_waitcnt vmcnt(0)" ::: "memory");
        }
        __builtin_amdgcn_s_barrier();
        bufc = (bufc + 1 == 3) ? 0 : bufc + 1;
    }

    const int sect = tn >> 10;
#pragma unroll
    for (int nf = 0; nf < 4; ++nf) {
        int col = tn + wc * 64 + nf * 16 + m;
        float bv = bf2f(bias[col]);
#pragma unroll
        for (int mf = 0; mf < 4; ++mf) {
            int rowb = tm + wr * 64 + mf * 16 + q * 4;
#pragma unroll
            for (int rg = 0; rg < 4; ++rg) {
                int t = rowb + rg;
                float v = acc[mf][nf][rg] + bv;
                if (relu) v = fmaxf(v, 0.f);
                size_t off;
                if (MODE == 0) {
                    off = (size_t)t * N + col;
                } else {
                    int c = col & 1023;
                    int bh = (t & 3) * 16 + (c >> 6);
                    if (sect == 0) {
                        off = (size_t)bh * 131072 + (t >> 2) * 64 + (c & 63);
                        v *= 0.18033688f;  // 1/(8*ln2)
                    } else if (sect == 1) {
                        off = 8388608ull + (size_t)bh * 131072 + (t >> 2) * 64 + (c & 63);
                    } else {
                        off = 16777216ull + (size_t)bh * 131072 + (size_t)(c & 63) * 2048 + (t >> 2);
                    }
                }
                C[off] = f2bf(v);
            }
        }
    }
}

// ---------- flash attention ----------
// Round-6: row-sum l computed via ones-column MFMA (Lacc) instead of 32 scalar
// psum adds/iter + shuffle epilogue. C/D row mapping of Lacc == Oa, so
// l for Oa[nb][j] is Lacc[j] directly. l now sums the same bf16 P that PV uses.
__global__ __launch_bounds__(256) void attn2(
    const uint16_t* __restrict__ Qh, const uint16_t* __restrict__ Kh,
    const uint16_t* __restrict__ Vt, uint16_t* __restrict__ CTX)
{
    __shared__ uint16_t sK[2][64 * 64];
    __shared__ uint16_t sV[2][64 * 64];

    const int tid = threadIdx.x;
    const int w = tid >> 6, ln = tid & 63;
    const int m5 = ln & 31, h5 = ln >> 5;
    const int bh = blockIdx.x, qt = blockIdx.y;
    const uint16_t* Qb = Qh + (size_t)bh * 131072;
    const uint16_t* Kb = Kh + (size_t)bh * 131072;
    const uint16_t* Vb = Vt + (size_t)bh * 131072;

    const int qrow = qt * 128 + w * 32 + m5;
    bf16x8 qf[4];
#pragma unroll
    for (int ks = 0; ks < 4; ++ks)
        qf[ks] = *(const bf16x8*)(Qb + (size_t)qrow * 64 + ks * 16 + h5 * 8);

    f32x16 Oa[2], Lacc;
#pragma unroll
    for (int nb = 0; nb < 2; ++nb)
#pragma unroll
        for (int i = 0; i < 16; ++i) Oa[nb][i] = 0.f;
#pragma unroll
    for (int i = 0; i < 16; ++i)Acc_init: Lacc[i] = 0.f;

    // all-ones bf16 B-fragment for the row-sum MFMA
    union { uint16_t u[8]; bf16x8 v; } one8;
#pragma unroll
    for (int i = 0; i < 8; ++i) one8.u[i] = 0x3F80;

    const int sr = tid >> 3;
    const int g = (tid & 7) ^ (sr & 7);

    {
        load_lds16(Kb + (size_t)sr * 64 + g * 8,            &sK[0][tid * 8]);
        load_lds16(Kb + (size_t)(sr + 32) * 64 + g * 8,     &sK[0][2048 + tid * 8]);
        load_lds16(Vb + (size_t)sr * 2048 + g * 8,          &sV[0][tid * 8]);
        load_lds16(Vb + (size_t)(sr + 32) * 2048 + g * 8,   &sV[0][2048 + tid * 8]);
    }

    for (int c = 0; c < 32; ++c) {
        const int cur = c & 1;
        __syncthreads();
        if (c + 1 < 32) {
            const int nc = c + 1;
            uint16_t* kd = &sK[cur ^ 1][0];
            uint16_t* vd = &sV[cur ^ 1][0];
            load_lds16(Kb + (size_t)(nc * 64 + sr) * 64 + g * 8,        kd + tid * 8);
            load_lds16(Kb + (size_t)(nc * 64 + sr + 32) * 64 + g * 8,   kd + 2048 + tid * 8);
            load_lds16(Vb + (size_t)sr * 2048 + nc * 64 + g * 8,        vd + tid * 8);
            load_lds16(Vb + (size_t)(sr + 32) * 2048 + nc * 64 + g * 8, vd + 2048 + tid * 8);
        }

        bf16x8 pf[4];
#pragma unroll
        for (int kb = 0; kb < 2; ++kb) {
            f32x16 acc;
#pragma unroll
            for (int i = 0; i < 16; ++i) acc[i] = 0.f;
#pragma unroll
            for (int ks = 0; ks < 4; ++ks) {
                int row = kb * 32 + m5;
                int ph = (2 * ks + h5) ^ (m5 & 7);
                bf16x8 kf = *(const bf16x8*)&sK[cur][row * 64 + ph * 8];
                acc = __builtin_amdgcn_mfma_f32_32x32x16_bf16(kf, qf[ks], acc, 0, 0, 0);
            }
#pragma unroll
            for (int ksl = 0; ksl < 2; ++ksl) {
                float p0 = exp2r(acc[8 * ksl + 0]);
                float p1 = exp2r(acc[8 * ksl + 1]);
                float p2 = exp2r(acc[8 * ksl + 2]);
                float p3 = exp2r(acc[8 * ksl + 3]);
                float p4 = exp2r(acc[8 * ksl + 4]);
                float p5 = exp2r(acc[8 * ksl + 5]);
                float p6 = exp2r(acc[8 * ksl + 6]);
                float p7 = exp2r(acc[8 * ksl + 7]);
                uint32_t x0 = pack2t(p0, p1);
                uint32_t x1 = pack2t(p2, p3);
                uint32_t y0 = pack2t(p4, p5);
                uint32_t y1 = pack2t(p6, p7);
                plane32_swap(x0, y0);
                plane32_swap(x1, y1);
                union { uint32_t u[4]; bf16x8 v; } pu;
                pu.u[0] = x0; pu.u[1] = x1; pu.u[2] = y0; pu.u[3] = y1;
                pf[kb * 2 + ksl] = pu.v;
            }
        }

#pragma unroll
        for (int ks = 0; ks < 4; ++ks) {
            Lacc = __builtin_amdgcn_mfma_f32_32x32x16_bf16(pf[ks], one8.v, Lacc, 0, 0, 0);
#pragma unroll
            for (int nb = 0; nb < 2; ++nb) {
                int vrow = nb * 32 + m5;
                int ph = (2 * ks + h5) ^ (m5 & 7);
                bf16x8 vf = *(const bf16x8*)&sV[cur][vrow * 64 + ph * 8];
                Oa[nb] = __builtin_amdgcn_mfma_f32_32x32x16_bf16(pf[ks], vf, Oa[nb], 0, 0, 0);
            }
        }
    }

    float Li[16];
#pragma unroll
    for (int j = 0; j < 16; ++j) Li[j] = 1.f / Lacc[j];

    const int b_ = bh >> 4, h_ = bh & 15;
#pragma unroll
    for (int nb = 0; nb < 2; ++nb)
#pragma unroll
        for (int a = 0; a < 4; ++a)
#pragma unroll
            for (int r = 0; r < 4; ++r) {
                int qr = r + 8 * a + 4 * h5;
                int s = qt * 128 + w * 32 + qr;
                int col = h_ * 64 + nb * 32 + m5;
                CTX[(size_t)(s * 4 + b_) * 1024 + col] = f2bf(Oa[nb][4 * a + r] * Li[4 * a + r]);
            }
}

// ---------- fused residual + LayerNorm ----------
template<bool RES_F32, bool OUT_F32>
__global__ __launch_bounds__(256) void ln_resid(
    const uint16_t* __restrict__ Y, const void* __restrict__ Xp,
    const float* __restrict__ G, const float* __restrict__ Bv,
    void* __restrict__ Op)
{
    const int row = blockIdx.x, tid = threadIdx.x;
    const size_t base = (size_t)row * 1024 + tid * 4;
    ushort4 yv = *(const ushort4*)(Y + base);
    float x0, x1, x2, x3;
    if (RES_F32) {
        float4 xv = *(const float4*)((const float*)Xp + base);
        x0 = xv.x; x1 = xv.y; x2 = xv.z; x3 = xv.w;
    } else {
        ushort4 xv = *(const ushort4*)((const uint16_t*)Xp + base);
        x0 = bf2f(xv.x); x1 = bf2f(xv.y); x2 = bf2f(xv.z); x3 = bf2f(xv.w);
    }
    float v0 = bf2f(yv.x) + x0;
    float v1 = bf2f(yv.y) + x1;
    float v2 = bf2f(yv.z) + x2;
    float v3 = bf2f(yv.w) + x3;
    float s = v0 + v1 + v2 + v3;
    float ss = v0 * v0 + v1 * v1 + v2 * v2 + v3 * v3;
#pragma unroll
    for (int off = 32; off > 0; off >>= 1) {
        s += __shfl_down(s, off);
        ss += __shfl_down(ss, off);
    }
    __shared__ float rs[4], rss[4];
    if ((tid & 63) == 0) { rs[tid >> 6] = s; rss[tid >> 6] = ss; }
    __syncthreads();
    float S = rs[0] + rs[1] + rs[2] + rs[3];
    float SS = rss[0] + rss[1] + rss[2] + rss[3];
    const float invn = 1.f / 1024.f;
    float mu = S * invn;
    float var = SS * invn - mu * mu;
    float rstd = rsqrtf(var + 1e-5f);
    float4 gv = *(const float4*)(G + tid * 4);
    float4 bv = *(const float4*)(Bv + tid * 4);
    float o0 = (v0 - mu) * rstd * gv.x + bv.x;
    float o1 = (v1 - mu) * rstd * gv.y + bv.y;
    float o2 = (v2 - mu) * rstd * gv.z + bv.z;
    float o3 = (v3 - mu) * rstd * gv.w + bv.w;
    if (OUT_F32) {
        float4 o = {o0, o1, o2, o3};
        *(float4*)((float*)Op + base) = o;
    } else {
        ushort4 o;
        o.x = f2bf(o0); o.y = f2bf(o1); o.z = f2bf(o2); o.w = f2bf(o3);
        *(ushort4*)((uint16_t*)Op + base) = o;
    }
}

// ---------- launch ----------
extern "C" void kernel_launch(void* const* d_in, const int* in_sizes, int n_in,
                              void* d_out, int out_size, void* d_ws, size_t ws_size,
                              hipStream_t stream)
{
    const float* X    = (const float*)d_in[0];
    const float* WQw  = (const float*)d_in[1];
    const float* WQb  = (const float*)d_in[2];
    const float* WKw  = (const float*)d_in[3];
    const float* WKb  = (const float*)d_in[4];
    const float* WVw  = (const float*)d_in[5];
    const float* WVb  = (const float*)d_in[6];
    const float* WOw  = (const float*)d_in[7];
    const float* WOb  = (const float*)d_in[8];
    const float* ln1g = (const float*)d_in[9];
    const float* ln1b = (const float*)d_in[10];
    const float* W1   = (const float*)d_in[11];
    const float* b1   = (const float*)d_in[12];
    const float* W2   = (const float*)d_in[13];
    const float* b2   = (const float*)d_in[14];
    const float* ln2g = (const float*)d_in[15];
    const float* ln2b = (const float*)d_in[16];

    uint16_t* ws = (uint16_t*)d_ws;
    const size_t E = 8192ull * 1024ull;
    const size_t MW = 1048576ull;
    uint16_t* Xb   = ws;
    uint16_t* qh   = ws + E;
    uint16_t* kh   = ws + 2 * E;
    uint16_t* vt   = ws + 3 * E;
    uint16_t* ctx  = ws + 4 * E;
    uint16_t* y    = qh;
    uint16_t* x1   = kh;
    uint16_t* m2   = vt;
    uint16_t* hbuf = ws + 5 * E;
    uint16_t* wq   = ws + 9 * E;
    uint16_t* wo   = wq + 3 * MW;
    uint16_t* w1   = wo + MW;
    uint16_t* w2   = w1 + 4 * MW;
    uint16_t* bq   = w2 + 4 * MW;
    uint16_t* bo   = bq + 3072;
    uint16_t* bb1  = bo + 1024;
    uint16_t* bb2  = bb1 + 4096;

    static bool attr_set = false;
    if (!attr_set) {
        (void)hipFuncSetAttribute(reinterpret_cast<const void*>(gemm8<3>),
                                  hipFuncAttributeMaxDynamicSharedMemorySize, 147456);
        attr_set = true;
    }

    cvt_all<<<dim3(20481), dim3(256), 0, stream>>>(
        X, WQw, WKw, WVw, WOw, W1, W2, WQb, WKb, WVb, WOb, b1, b2,
        Xb, wq, bq);

    dim3 blk(256);
    // QKV: gemm8 256x128 tiles over [8192, 3072] -> 768 blocks (measured best)
    gemm8<3><<<dim3(768), dim3(512), 147456, stream>>>(Xb, wq, bq, qh, 1024, 3072, 24, 0);
    attn2<<<dim3(64, 16), blk, 0, stream>>>(qh, kh, vt, ctx);
    gemm_bt<0, 64><<<dim3(16, 64),  blk, 0, stream>>>(ctx,  wo, bo,  y,    1024, 1024, 0);
    ln_resid<true, false><<<dim3(8192), blk, 0, stream>>>(y, X, ln1g, ln1b, x1);
    // W1: gemm_bt 128x128 (measured 97.2 vs gemm8 100.1)
    gemm_bt<0, 128><<<dim3(32, 64), blk, 0, stream>>>(x1,   w1, bb1, hbuf, 1024, 4096, 1);
    // W2: NT=64 -> NT=128 (2x staging intensity at K=4096; 512 blocks = 2/CU)
    gemm_bt<0, 128><<<dim3(8, 64),  blk, 0, stream>>>(hbuf, w2, bb2, m2,   4096, 1024, 0);
    ln_resid<false, true><<<dim3(8192), blk, 0, stream>>>(m2, x1, ln2g, ln2b, d_out);
}

// Round 7
// 569.219 us; speedup vs baseline: 1.0067x; 1.0067x over previous
//
#include <hip/hip_runtime.h>
#include <stdint.h>

// ---------- types & helpers ----------
typedef short bf16x8 __attribute__((ext_vector_type(8)));
typedef float f32x4 __attribute__((ext_vector_type(4)));
typedef float f32x16 __attribute__((ext_vector_type(16)));

__device__ __forceinline__ float bf2f(uint16_t u) {
    union { uint32_t i; float f; } c; c.i = ((uint32_t)u) << 16; return c.f;
}
__device__ __forceinline__ uint16_t f2bf(float f) {
    union { float f; uint32_t i; } c; c.f = f;
    uint32_t x = c.i;
    return (uint16_t)((x + 0x7fffu + ((x >> 16) & 1u)) >> 16);  // RNE
}
// truncating pack: (bf16(hi)<<16)|bf16(lo) — OK for all-positive P
__device__ __forceinline__ uint32_t pack2t(float lo, float hi) {
    union { float f; uint32_t u; } a, b;
    a.f = lo; b.f = hi;
    return __builtin_amdgcn_perm(b.u, a.u, 0x07060302u);
}

// raw v_exp_f32 (2^x) — skips OCML denormal-range fixup; scores are bounded
__device__ __forceinline__ float exp2r(float x) {
#if __has_builtin(__builtin_amdgcn_exp2f)
    return __builtin_amdgcn_exp2f(x);
#else
    return exp2f(x);
#endif
}

// v_permlane32_swap_b32:
// post: a[l<32]=a_old[l], a[l>=32]=b_old[l-32];  b[l<32]=a_old[l+32], b[l>=32]=b_old[l]
__device__ __forceinline__ void plane32_swap(uint32_t& a, uint32_t& b) {
#if __has_builtin(__builtin_amdgcn_permlane32_swap)
    typedef unsigned int u32x2 __attribute__((ext_vector_type(2)));
    u32x2 r = __builtin_amdgcn_permlane32_swap(a, b, false, false);
    a = r[0]; b = r[1];
#else
    asm volatile("v_permlane32_swap_b32 %0, %1" : "+v"(a), "+v"(b));
#endif
}

// async global->LDS, 16B per lane; LDS dest = wave-uniform base + lane*16
__device__ __forceinline__ void load_lds16(const void* g, void* lds) {
    using gp_t = const __attribute__((address_space(1))) uint32_t*;
    using lp_t = __attribute__((address_space(3))) uint32_t*;
    __builtin_amdgcn_global_load_lds(
        reinterpret_cast<gp_t>(reinterpret_cast<uintptr_t>(g)),
        reinterpret_cast<lp_t>((uint32_t)reinterpret_cast<uintptr_t>(lds)),
        16, 0, 0);
}

// ---------- single-launch fp32 -> bf16 convert for all inputs ----------
__global__ __launch_bounds__(256) void cvt_all(
    const float* __restrict__ X,
    const float* __restrict__ wqf, const float* __restrict__ wkf,
    const float* __restrict__ wvf, const float* __restrict__ wof,
    const float* __restrict__ w1f, const float* __restrict__ w2f,
    const float* __restrict__ bqf, const float* __restrict__ bkf,
    const float* __restrict__ bvf, const float* __restrict__ bof,
    const float* __restrict__ b1f, const float* __restrict__ b2f,
    uint16_t* __restrict__ Xb, uint16_t* __restrict__ wd, uint16_t* __restrict__ bd)
{
    const int b = blockIdx.x, tid = threadIdx.x;
    const size_t M = 1048576ull;
    const float* s; uint16_t* d; size_t i, off;
    if (b < 8192) {
        i = ((size_t)b * 256 + tid) * 4;
        s = X; off = i; d = Xb;
    } else if (b < 20480) {
        i = ((size_t)(b - 8192) * 256 + tid) * 4;
        d = wd;
        if (i < M)           { s = wqf; off = i; }
        else if (i < 2 * M)  { s = wkf; off = i - M; }
        else if (i < 3 * M)  { s = wvf; off = i - 2 * M; }
        else if (i < 4 * M)  { s = wof; off = i - 3 * M; }
        else if (i < 8 * M)  { s = w1f; off = i - 4 * M; }
        else                 { s = w2f; off = i - 8 * M; }
    } else {
        int j = tid * 4;
        d = bd;
        for (int p = 0; p < 9; ++p, j += 1024) {
            const float* sb; int ob;
            if (j < 1024)      { sb = bqf; ob = j; }
            else if (j < 2048) { sb = bkf; ob = j - 1024; }
            else if (j < 3072) { sb = bvf; ob = j - 2048; }
            else if (j < 4096) { sb = bof; ob = j - 3072; }
            else if (j < 8192) { sb = b1f; ob = j - 4096; }
            else               { sb = b2f; ob = j - 8192; }
            float4 x = *(const float4*)(sb + ob);
            ushort4 u;
            u.x = f2bf(x.x); u.y = f2bf(x.y); u.z = f2bf(x.z); u.w = f2bf(x.w);
            *(ushort4*)(d + j) = u;
        }
        return;
    }
    float4 x = *(const float4*)(s + off);
    ushort4 u;
    u.x = f2bf(x.x); u.y = f2bf(x.y); u.z = f2bf(x.z); u.w = f2bf(x.w);
    *(ushort4*)(d + i) = u;
}

// ---------- generic bf16 GEMM (m97-class 128xNT) ----------
template<int MODE, int NT>
__global__ __launch_bounds__(256) void gemm_bt(
    const uint16_t* __restrict__ A, const uint16_t* __restrict__ B,
    const uint16_t* __restrict__ bias, uint16_t* __restrict__ C,
    int K, int N, int relu)
{
    const int CT = NT / 32;
    __shared__ uint16_t sA[128 * 64];
    __shared__ uint16_t sB[NT * 64];
    const int tid = threadIdx.x;
    const int w = tid >> 6, ln = tid & 63;
    const int m = ln & 15, q = ln >> 4;
    const int wr = w >> 1, wc = w & 1;
    const int tm = blockIdx.y * 128, tn = blockIdx.x * NT;

    f32x4 zero = {0.f, 0.f, 0.f, 0.f};
    f32x4 acc[4][CT];
#pragma unroll
    for (int i = 0; i < 4; ++i)
#pragma unroll
        for (int j = 0; j < CT; ++j) acc[i][j] = zero;

    const int sr = tid >> 3;
    const int sc_ = tid & 7;
    const int g = sc_ ^ (sr & 7);

    for (int k0 = 0; k0 < K; k0 += 64) {
        __syncthreads();
#pragma unroll
        for (int i = 0; i < 4; ++i) {
            int r = i * 32 + sr;
            load_lds16(A + (size_t)(tm + r) * K + k0 + g * 8, &sA[(i * 32 + w * 8) * 64]);
        }
#pragma unroll
        for (int i = 0; i < NT / 32; ++i) {
            int r = i * 32 + sr;
            load_lds16(B + (size_t)(tn + r) * K + k0 + g * 8, &sB[(i * 32 + w * 8) * 64]);
        }
        __syncthreads();
#pragma unroll
        for (int kk = 0; kk < 2; ++kk) {
            bf16x8 af[4], bfr[CT];
            const int s = (kk * 4 + q) ^ (m & 7);
#pragma unroll
            for (int rt = 0; rt < 4; ++rt) {
                int R = wr * 64 + rt * 16 + m;
                af[rt] = *(const bf16x8*)&sA[R * 64 + s * 8];
            }
#pragma unroll
            for (int ct = 0; ct < CT; ++ct) {
                int R = wc * (NT / 2) + ct * 16 + m;
                bfr[ct] = *(const bf16x8*)&sB[R * 64 + s * 8];
            }
#pragma unroll
            for (int rt = 0; rt < 4; ++rt)
#pragma unroll
                for (int ct = 0; ct < CT; ++ct)
                    acc[rt][ct] = __builtin_amdgcn_mfma_f32_16x16x32_bf16(
                        af[rt], bfr[ct], acc[rt][ct], 0, 0, 0);
        }
    }

#pragma unroll
    for (int ct = 0; ct < CT; ++ct) {
        int col = tn + wc * (NT / 2) + ct * 16 + m;
        float bv = bf2f(bias[col]);
#pragma unroll
        for (int rt = 0; rt < 4; ++rt) {
            int rowb = tm + wr * 64 + rt * 16 + q * 4;
#pragma unroll
            for (int rg = 0; rg < 4; ++rg) {
                int t = rowb + rg;
                float v = acc[rt][ct][rg] + bv;
                if (relu) v = fmaxf(v, 0.f);
                C[(size_t)t * N + col] = f2bf(v);
            }
        }
    }
}

// ---------- 256x128 8-wave GEMM, triple-buffered counted-vmcnt pipeline ----------
// (QKV only — measured 98.0 us there, best observed for that dispatch)
template<int MODE>
__global__ __launch_bounds__(512, 2) void gemm8(
    const uint16_t* __restrict__ A, const uint16_t* __restrict__ B,
    const uint16_t* __restrict__ bias, uint16_t* __restrict__ C,
    int K, int N, int NBX, int relu)
{
    extern __shared__ uint16_t smem[];

    const int tid = threadIdx.x;
    const int w = tid >> 6, ln = tid & 63;
    const int m = ln & 15, q = ln >> 4;
    const int wr = w >> 1, wc = w & 1;

    const int nwg = gridDim.x;
    const int bid = blockIdx.x;
    const int wg = (bid & 7) * (nwg >> 3) + (bid >> 3);
    const int bx = wg % NBX, by = wg / NBX;
    const int tm = by * 256, tn = bx * 128;

    const int sr = tid >> 3;
    const int g = (tid & 7) ^ (sr & 7);
    const int wbase = w * 512;
    const int KT = K >> 6;

    f32x4 acc[4][4];
#pragma unroll
    for (int i = 0; i < 4; ++i)
#pragma unroll
        for (int j = 0; j < 4; ++j) acc[i][j] = f32x4{0.f, 0.f, 0.f, 0.f};

    auto stageA2 = [&](int buf, int t, int i0) {
        uint16_t* dA = smem + buf * 24576;
#pragma unroll
        for (int i = i0; i < i0 + 2; ++i)
            load_lds16(A + (size_t)(tm + i * 64 + sr) * K + t * 64 + g * 8,
                       dA + i * 4096 + wbase);
    };
    auto stageB1 = [&](int buf, int t, int i) {
        uint16_t* dB = smem + buf * 24576 + 16384;
        load_lds16(B + (size_t)(tn + i * 64 + sr) * K + t * 64 + g * 8,
                   dB + i * 4096 + wbase);
    };

    stageA2(0, 0, 0); stageA2(0, 0, 2); stageB1(0, 0, 0); stageB1(0, 0, 1);
    stageA2(1, 1, 0); stageA2(1, 1, 2); stageB1(1, 1, 0); stageB1(1, 1, 1);
    asm volatile("s_waitcnt vmcnt(6)" ::: "memory");
    __builtin_amdgcn_s_barrier();

    int bufc = 0;
    for (int t = 0; t < KT; ++t) {
        const uint16_t* pA = smem + bufc * 24576;
        const uint16_t* pB = pA + 16384;
        int bufn = bufc + 2; if (bufn >= 3) bufn -= 3;
        const bool pf = (t + 2 < KT);

        bf16x8 af[4], bfr[4];

        {
            const int s = q ^ (m & 7);
#pragma unroll
            for (int mf = 0; mf < 4; ++mf)
                af[mf] = *(const bf16x8*)&pA[(wr * 64 + mf * 16 + m) * 64 + s * 8];
#pragma unroll
            for (int nf = 0; nf < 4; ++nf)
                bfr[nf] = *(const bf16x8*)&pB[(wc * 64 + nf * 16 + m) * 64 + s * 8];
        }
        if (pf) { stageA2(bufn, t + 2, 0); stageB1(bufn, t + 2, 0); }
        __builtin_amdgcn_s_barrier();
        asm volatile("s_waitcnt lgkmcnt(0)" ::: "memory");
        __builtin_amdgcn_sched_barrier(0);
        __builtin_amdgcn_s_setprio(1);
#pragma unroll
        for (int mf = 0; mf < 4; ++mf)
#pragma unroll
            for (int nf = 0; nf < 4; ++nf)
                acc[mf][nf] = __builtin_amdgcn_mfma_f32_16x16x32_bf16(
                    af[mf], bfr[nf], acc[mf][nf], 0, 0, 0);
        __builtin_amdgcn_s_setprio(0);
        __builtin_amdgcn_s_barrier();

        {
            const int s = (4 + q) ^ (m & 7);
#pragma unroll
            for (int mf = 0; mf < 4; ++mf)
                af[mf] = *(const bf16x8*)&pA[(wr * 64 + mf * 16 + m) * 64 + s * 8];
#pragma unroll
            for (int nf = 0; nf < 4; ++nf)
                bfr[nf] = *(const bf16x8*)&pB[(wc * 64 + nf * 16 + m) * 64 + s * 8];
        }
        if (pf) { stageA2(bufn, t + 2, 2); stageB1(bufn, t + 2, 1); }
        __builtin_amdgcn_s_barrier();
        asm volatile("s_waitcnt lgkmcnt(0)" ::: "memory");
        __builtin_amdgcn_sched_barrier(0);
        __builtin_amdgcn_s_setprio(1);
#pragma unroll
        for (int mf = 0; mf < 4; ++mf)
#pragma unroll
            for (int nf = 0; nf < 4; ++nf)
                acc[mf][nf] = __builtin_amdgcn_mfma_f32_16x16x32_bf16(
                    af[mf], bfr[nf], acc[mf][nf], 0, 0, 0);
        __builtin_amdgcn_s_setprio(0);
        if (t + 1 < KT) {
            if (pf) asm volatile("s_waitcnt vmcnt(6)" ::: "memory");
            else    asm volatile("s_waitcnt vmcnt(0)" ::: "memory");
        }
        __builtin_amdgcn_s_barrier();
        bufc = (bufc + 1 == 3) ? 0 : bufc + 1;
    }

    const int sect = tn >> 10;
#pragma unroll
    for (int nf = 0; nf < 4; ++nf) {
        int col = tn + wc * 64 + nf * 16 + m;
        float bv = bf2f(bias[col]);
#pragma unroll
        for (int mf = 0; mf < 4; ++mf) {
            int rowb = tm + wr * 64 + mf * 16 + q * 4;
#pragma unroll
            for (int rg = 0; rg < 4; ++rg) {
                int t = rowb + rg;
                float v = acc[mf][nf][rg] + bv;
                if (relu) v = fmaxf(v, 0.f);
                size_t off;
                if (MODE == 0) {
                    off = (size_t)t * N + col;
                } else {
                    int c = col & 1023;
                    int bh = (t & 3) * 16 + (c >> 6);
                    if (sect == 0) {
                        off = (size_t)bh * 131072 + (t >> 2) * 64 + (c & 63);
                        v *= 0.18033688f;  // 1/(8*ln2)
                    } else if (sect == 1) {
                        off = 8388608ull + (size_t)bh * 131072 + (t >> 2) * 64 + (c & 63);
                    } else {
                        off = 16777216ull + (size_t)bh * 131072 + (size_t)(c & 63) * 2048 + (t >> 2);
                    }
                }
                C[off] = f2bf(v);
            }
        }
    }
}

// ---------- flash attention ----------
// Row-sum l via ones-column MFMA (Lacc): C/D row mapping of Lacc == Oa, so
// l for Oa[nb][j] is Lacc[j] directly; deletes 32 VALU adds/iter + shuffle epi.
__global__ __launch_bounds__(256) void attn2(
    const uint16_t* __restrict__ Qh, const uint16_t* __restrict__ Kh,
    const uint16_t* __restrict__ Vt, uint16_t* __restrict__ CTX)
{
    __shared__ uint16_t sK[2][64 * 64];
    __shared__ uint16_t sV[2][64 * 64];

    const int tid = threadIdx.x;
    const int w = tid >> 6, ln = tid & 63;
    const int m5 = ln & 31, h5 = ln >> 5;
    const int bh = blockIdx.x, qt = blockIdx.y;
    const uint16_t* Qb = Qh + (size_t)bh * 131072;
    const uint16_t* Kb = Kh + (size_t)bh * 131072;
    const uint16_t* Vb = Vt + (size_t)bh * 131072;

    const int qrow = qt * 128 + w * 32 + m5;
    bf16x8 qf[4];
#pragma unroll
    for (int ks = 0; ks < 4; ++ks)
        qf[ks] = *(const bf16x8*)(Qb + (size_t)qrow * 64 + ks * 16 + h5 * 8);

    f32x16 Oa[2], Lacc;
#pragma unroll
    for (int nb = 0; nb < 2; ++nb)
#pragma unroll
        for (int i = 0; i < 16; ++i) Oa[nb][i] = 0.f;
#pragma unroll
    for (int i = 0; i < 16; ++i) Lacc[i] = 0.f;

    // all-ones bf16 B-fragment for the row-sum MFMA
    union { uint16_t u[8]; bf16x8 v; } one8;
#pragma unroll
    for (int i = 0; i < 8; ++i) one8.u[i] = 0x3F80;

    const int sr = tid >> 3;
    const int g = (tid & 7) ^ (sr & 7);

    {
        load_lds16(Kb + (size_t)sr * 64 + g * 8,            &sK[0][tid * 8]);
        load_lds16(Kb + (size_t)(sr + 32) * 64 + g * 8,     &sK[0][2048 + tid * 8]);
        load_lds16(Vb + (size_t)sr * 2048 + g * 8,          &sV[0][tid * 8]);
        load_lds16(Vb + (size_t)(sr + 32) * 2048 + g * 8,   &sV[0][2048 + tid * 8]);
    }

    for (int c = 0; c < 32; ++c) {
        const int cur = c & 1;
        __syncthreads();
        if (c + 1 < 32) {
            const int nc = c + 1;
            uint16_t* kd = &sK[cur ^ 1][0];
            uint16_t* vd = &sV[cur ^ 1][0];
            load_lds16(Kb + (size_t)(nc * 64 + sr) * 64 + g * 8,        kd + tid * 8);
            load_lds16(Kb + (size_t)(nc * 64 + sr + 32) * 64 + g * 8,   kd + 2048 + tid * 8);
            load_lds16(Vb + (size_t)sr * 2048 + nc * 64 + g * 8,        vd + tid * 8);
            load_lds16(Vb + (size_t)(sr + 32) * 2048 + nc * 64 + g * 8, vd + 2048 + tid * 8);
        }

        bf16x8 pf[4];
#pragma unroll
        for (int kb = 0; kb < 2; ++kb) {
            f32x16 acc;
#pragma unroll
            for (int i = 0; i < 16; ++i) acc[i] = 0.f;
#pragma unroll
            for (int ks = 0; ks < 4; ++ks) {
                int row = kb * 32 + m5;
                int ph = (2 * ks + h5) ^ (m5 & 7);
                bf16x8 kf = *(const bf16x8*)&sK[cur][row * 64 + ph * 8];
                acc = __builtin_amdgcn_mfma_f32_32x32x16_bf16(kf, qf[ks], acc, 0, 0, 0);
            }
#pragma unroll
            for (int ksl = 0; ksl < 2; ++ksl) {
                float p0 = exp2r(acc[8 * ksl + 0]);
                float p1 = exp2r(acc[8 * ksl + 1]);
                float p2 = exp2r(acc[8 * ksl + 2]);
                float p3 = exp2r(acc[8 * ksl + 3]);
                float p4 = exp2r(acc[8 * ksl + 4]);
                float p5 = exp2r(acc[8 * ksl + 5]);
                float p6 = exp2r(acc[8 * ksl + 6]);
                float p7 = exp2r(acc[8 * ksl + 7]);
                uint32_t x0 = pack2t(p0, p1);
                uint32_t x1 = pack2t(p2, p3);
                uint32_t y0 = pack2t(p4, p5);
                uint32_t y1 = pack2t(p6, p7);
                plane32_swap(x0, y0);
                plane32_swap(x1, y1);
                union { uint32_t u[4]; bf16x8 v; } pu;
                pu.u[0] = x0; pu.u[1] = x1; pu.u[2] = y0; pu.u[3] = y1;
                pf[kb * 2 + ksl] = pu.v;
            }
        }

#pragma unroll
        for (int ks = 0; ks < 4; ++ks) {
            Lacc = __builtin_amdgcn_mfma_f32_32x32x16_bf16(pf[ks], one8.v, Lacc, 0, 0, 0);
#pragma unroll
            for (int nb = 0; nb < 2; ++nb) {
                int vrow = nb * 32 + m5;
                int ph = (2 * ks + h5) ^ (m5 & 7);
                bf16x8 vf = *(const bf16x8*)&sV[cur][vrow * 64 + ph * 8];
                Oa[nb] = __builtin_amdgcn_mfma_f32_32x32x16_bf16(pf[ks], vf, Oa[nb], 0, 0, 0);
            }
        }
    }

    float Li[16];
#pragma unroll
    for (int j = 0; j < 16; ++j) Li[j] = 1.f / Lacc[j];

    const int b_ = bh >> 4, h_ = bh & 15;
#pragma unroll
    for (int nb = 0; nb < 2; ++nb)
#pragma unroll
        for (int a = 0; a < 4; ++a)
#pragma unroll
            for (int r = 0; r < 4; ++r) {
                int qr = r + 8 * a + 4 * h5;
                int s = qt * 128 + w * 32 + qr;
                int col = h_ * 64 + nb * 32 + m5;
                CTX[(size_t)(s * 4 + b_) * 1024 + col] = f2bf(Oa[nb][4 * a + r] * Li[4 * a + r]);
            }
}

// ---------- fused residual + LayerNorm ----------
template<bool RES_F32, bool OUT_F32>
__global__ __launch_bounds__(256) void ln_resid(
    const uint16_t* __restrict__ Y, const void* __restrict__ Xp,
    const float* __restrict__ G, const float* __restrict__ Bv,
    void* __restrict__ Op)
{
    const int row = blockIdx.x, tid = threadIdx.x;
    const size_t base = (size_t)row * 1024 + tid * 4;
    ushort4 yv = *(const ushort4*)(Y + base);
    float x0, x1, x2, x3;
    if (RES_F32) {
        float4 xv = *(const float4*)((const float*)Xp + base);
        x0 = xv.x; x1 = xv.y; x2 = xv.z; x3 = xv.w;
    } else {
        ushort4 xv = *(const ushort4*)((const uint16_t*)Xp + base);
        x0 = bf2f(xv.x); x1 = bf2f(xv.y); x2 = bf2f(xv.z); x3 = bf2f(xv.w);
    }
    float v0 = bf2f(yv.x) + x0;
    float v1 = bf2f(yv.y) + x1;
    float v2 = bf2f(yv.z) + x2;
    float v3 = bf2f(yv.w) + x3;
    float s = v0 + v1 + v2 + v3;
    float ss = v0 * v0 + v1 * v1 + v2 * v2 + v3 * v3;
#pragma unroll
    for (int off = 32; off > 0; off >>= 1) {
        s += __shfl_down(s, off);
        ss += __shfl_down(ss, off);
    }
    __shared__ float rs[4], rss[4];
    if ((tid & 63) == 0) { rs[tid >> 6] = s; rss[tid >> 6] = ss; }
    __syncthreads();
    float S = rs[0] + rs[1] + rs[2] + rs[3];
    float SS = rss[0] + rss[1] + rss[2] + rss[3];
    const float invn = 1.f / 1024.f;
    float mu = S * invn;
    float var = SS * invn - mu * mu;
    float rstd = rsqrtf(var + 1e-5f);
    float4 gv = *(const float4*)(G + tid * 4);
    float4 bv = *(const float4*)(Bv + tid * 4);
    float o0 = (v0 - mu) * rstd * gv.x + bv.x;
    float o1 = (v1 - mu) * rstd * gv.y + bv.y;
    float o2 = (v2 - mu) * rstd * gv.z + bv.z;
    float o3 = (v3 - mu) * rstd * gv.w + bv.w;
    if (OUT_F32) {
        float4 o = {o0, o1, o2, o3};
        *(float4*)((float*)Op + base) = o;
    } else {
        ushort4 o;
        o.x = f2bf(o0); o.y = f2bf(o1); o.z = f2bf(o2); o.w = f2bf(o3);
        *(ushort4*)((uint16_t*)Op + base) = o;
    }
}

// ---------- launch ----------
extern "C" void kernel_launch(void* const* d_in, const int* in_sizes, int n_in,
                              void* d_out, int out_size, void* d_ws, size_t ws_size,
                              hipStream_t stream)
{
    const float* X    = (const float*)d_in[0];
    const float* WQw  = (const float*)d_in[1];
    const float* WQb  = (const float*)d_in[2];
    const float* WKw  = (const float*)d_in[3];
    const float* WKb  = (const float*)d_in[4];
    const float* WVw  = (const float*)d_in[5];
    const float* WVb  = (const float*)d_in[6];
    const float* WOw  = (const float*)d_in[7];
    const float* WOb  = (const float*)d_in[8];
    const float* ln1g = (const float*)d_in[9];
    const float* ln1b = (const float*)d_in[10];
    const float* W1   = (const float*)d_in[11];
    const float* b1   = (const float*)d_in[12];
    const float* W2   = (const float*)d_in[13];
    const float* b2   = (const float*)d_in[14];
    const float* ln2g = (const float*)d_in[15];
    const float* ln2b = (const float*)d_in[16];

    uint16_t* ws = (uint16_t*)d_ws;
    const size_t E = 8192ull * 1024ull;
    const size_t MW = 1048576ull;
    uint16_t* Xb   = ws;
    uint16_t* qh   = ws + E;
    uint16_t* kh   = ws + 2 * E;
    uint16_t* vt   = ws + 3 * E;
    uint16_t* ctx  = ws + 4 * E;
    uint16_t* y    = qh;
    uint16_t* x1   = kh;
    uint16_t* m2   = vt;
    uint16_t* hbuf = ws + 5 * E;
    uint16_t* wq   = ws + 9 * E;
    uint16_t* wo   = wq + 3 * MW;
    uint16_t* w1   = wo + MW;
    uint16_t* w2   = w1 + 4 * MW;
    uint16_t* bq   = w2 + 4 * MW;
    uint16_t* bo   = bq + 3072;
    uint16_t* bb1  = bo + 1024;
    uint16_t* bb2  = bb1 + 4096;

    static bool attr_set = false;
    if (!attr_set) {
        (void)hipFuncSetAttribute(reinterpret_cast<const void*>(gemm8<3>),
                                  hipFuncAttributeMaxDynamicSharedMemorySize, 147456);
        attr_set = true;
    }

    cvt_all<<<dim3(20481), dim3(256), 0, stream>>>(
        X, WQw, WKw, WVw, WOw, W1, W2, WQb, WKb, WVb, WOb, b1, b2,
        Xb, wq, bq);

    dim3 blk(256);
    // QKV: gemm8 256x128 tiles over [8192, 3072] -> 768 blocks (measured 98.0)
    gemm8<3><<<dim3(768), dim3(512), 147456, stream>>>(Xb, wq, bq, qh, 1024, 3072, 24, 0);
    attn2<<<dim3(64, 16), blk, 0, stream>>>(qh, kh, vt, ctx);
    gemm_bt<0, 64><<<dim3(16, 64),  blk, 0, stream>>>(ctx,  wo, bo,  y,    1024, 1024, 0);
    ln_resid<true, false><<<dim3(8192), blk, 0, stream>>>(y, X, ln1g, ln1b, x1);
    // W1: gemm_bt 128x128 (measured 97.5 vs gemm8 100.1)
    gemm_bt<0, 128><<<dim3(32, 64), blk, 0, stream>>>(x1,   w1, bb1, hbuf, 1024, 4096, 1);
    // W2: reverted to NT=64 (NT=128 measured 97.5us / 266MB FETCH — regression)
    gemm_bt<0, 64><<<dim3(16, 64),  blk, 0, stream>>>(hbuf, w2, bb2, m2,   4096, 1024, 0);
    ln_resid<false, true><<<dim3(8192), blk, 0, stream>>>(m2, x1, ln2g, ln2b, d_out);
}

// Round 8
// 559.306 us; speedup vs baseline: 1.0246x; 1.0177x over previous
//
#include <hip/hip_runtime.h>
#include <stdint.h>

// ---------- types & helpers ----------
typedef short bf16x8 __attribute__((ext_vector_type(8)));
typedef float f32x4 __attribute__((ext_vector_type(4)));
typedef float f32x16 __attribute__((ext_vector_type(16)));

__device__ __forceinline__ float bf2f(uint16_t u) {
    union { uint32_t i; float f; } c; c.i = ((uint32_t)u) << 16; return c.f;
}
__device__ __forceinline__ uint16_t f2bf(float f) {
    union { float f; uint32_t i; } c; c.f = f;
    uint32_t x = c.i;
    return (uint16_t)((x + 0x7fffu + ((x >> 16) & 1u)) >> 16);  // RNE
}
// truncating pack: (bf16(hi)<<16)|bf16(lo) — OK for all-positive P
__device__ __forceinline__ uint32_t pack2t(float lo, float hi) {
    union { float f; uint32_t u; } a, b;
    a.f = lo; b.f = hi;
    return __builtin_amdgcn_perm(b.u, a.u, 0x07060302u);
}

// raw v_exp_f32 (2^x) — skips OCML denormal-range fixup; scores are bounded
__device__ __forceinline__ float exp2r(float x) {
#if __has_builtin(__builtin_amdgcn_exp2f)
    return __builtin_amdgcn_exp2f(x);
#else
    return exp2f(x);
#endif
}

// v_permlane32_swap_b32:
// post: a[l<32]=a_old[l], a[l>=32]=b_old[l-32];  b[l<32]=a_old[l+32], b[l>=32]=b_old[l]
__device__ __forceinline__ void plane32_swap(uint32_t& a, uint32_t& b) {
#if __has_builtin(__builtin_amdgcn_permlane32_swap)
    typedef unsigned int u32x2 __attribute__((ext_vector_type(2)));
    u32x2 r = __builtin_amdgcn_permlane32_swap(a, b, false, false);
    a = r[0]; b = r[1];
#else
    asm volatile("v_permlane32_swap_b32 %0, %1" : "+v"(a), "+v"(b));
#endif
}

// async global->LDS, 16B per lane; LDS dest = wave-uniform base + lane*16
__device__ __forceinline__ void load_lds16(const void* g, void* lds) {
    using gp_t = const __attribute__((address_space(1))) uint32_t*;
    using lp_t = __attribute__((address_space(3))) uint32_t*;
    __builtin_amdgcn_global_load_lds(
        reinterpret_cast<gp_t>(reinterpret_cast<uintptr_t>(g)),
        reinterpret_cast<lp_t>((uint32_t)reinterpret_cast<uintptr_t>(lds)),
        16, 0, 0);
}

// ---------- single-launch fp32 -> bf16 convert for all inputs ----------
__global__ __launch_bounds__(256) void cvt_all(
    const float* __restrict__ X,
    const float* __restrict__ wqf, const float* __restrict__ wkf,
    const float* __restrict__ wvf, const float* __restrict__ wof,
    const float* __restrict__ w1f, const float* __restrict__ w2f,
    const float* __restrict__ bqf, const float* __restrict__ bkf,
    const float* __restrict__ bvf, const float* __restrict__ bof,
    const float* __restrict__ b1f, const float* __restrict__ b2f,
    uint16_t* __restrict__ Xb, uint16_t* __restrict__ wd, uint16_t* __restrict__ bd)
{
    const int b = blockIdx.x, tid = threadIdx.x;
    const size_t M = 1048576ull;
    const float* s; uint16_t* d; size_t i, off;
    if (b < 8192) {
        i = ((size_t)b * 256 + tid) * 4;
        s = X; off = i; d = Xb;
    } else if (b < 20480) {
        i = ((size_t)(b - 8192) * 256 + tid) * 4;
        d = wd;
        if (i < M)           { s = wqf; off = i; }
        else if (i < 2 * M)  { s = wkf; off = i - M; }
        else if (i < 3 * M)  { s = wvf; off = i - 2 * M; }
        else if (i < 4 * M)  { s = wof; off = i - 3 * M; }
        else if (i < 8 * M)  { s = w1f; off = i - 4 * M; }
        else                 { s = w2f; off = i - 8 * M; }
    } else {
        int j = tid * 4;
        d = bd;
        for (int p = 0; p < 9; ++p, j += 1024) {
            const float* sb; int ob;
            if (j < 1024)      { sb = bqf; ob = j; }
            else if (j < 2048) { sb = bkf; ob = j - 1024; }
            else if (j < 3072) { sb = bvf; ob = j - 2048; }
            else if (j < 4096) { sb = bof; ob = j - 3072; }
            else if (j < 8192) { sb = b1f; ob = j - 4096; }
            else               { sb = b2f; ob = j - 8192; }
            float4 x = *(const float4*)(sb + ob);
            ushort4 u;
            u.x = f2bf(x.x); u.y = f2bf(x.y); u.z = f2bf(x.z); u.w = f2bf(x.w);
            *(ushort4*)(d + j) = u;
        }
        return;
    }
    float4 x = *(const float4*)(s + off);
    ushort4 u;
    u.x = f2bf(x.x); u.y = f2bf(x.y); u.z = f2bf(x.z); u.w = f2bf(x.w);
    *(ushort4*)(d + i) = u;
}

// ---------- generic bf16 GEMM: C = A[M,K] @ B[N,K]^T + bias (opt relu) ----------
// 128xNT tile, BK=64, 256 threads (4 waves, 2x2). Multi-block/CU overlap is the
// pipelining mechanism (m114) — measured best structure in this pipeline.
// MODE 0: C[t*N+col] linear.  MODE 3: fused QKV scatter (N=3072, NT=128).
// SWZ 1: 1-D grid, M-major XCD mapping — XCD = lin&7 owns contiguous M-tiles
//        (fixes W2's A-restream: B-panels L2-resident, A fetched ~once).
template<int MODE, int NT, int SWZ>
__global__ __launch_bounds__(256) void gemm_bt(
    const uint16_t* __restrict__ A, const uint16_t* __restrict__ B,
    const uint16_t* __restrict__ bias, uint16_t* __restrict__ C,
    int K, int N, int nbx, int relu)
{
    const int CT = NT / 32;
    __shared__ uint16_t sA[128 * 64];
    __shared__ uint16_t sB[NT * 64];
    const int tid = threadIdx.x;
    const int w = tid >> 6, ln = tid & 63;
    const int m = ln & 15, q = ln >> 4;
    const int wr = w >> 1, wc = w & 1;

    int bx, by;
    if (SWZ) {
        const int lin = blockIdx.x;
        const int xcd = lin & 7, idx = lin >> 3;
        const int per = (gridDim.x >> 3) / nbx;   // M-groups per XCD
        by = xcd * per + idx / nbx;
        bx = idx % nbx;
    } else {
        bx = blockIdx.x; by = blockIdx.y;
    }
    const int tm = by * 128, tn = bx * NT;

    f32x4 zero = {0.f, 0.f, 0.f, 0.f};
    f32x4 acc[4][CT];
#pragma unroll
    for (int i = 0; i < 4; ++i)
#pragma unroll
        for (int j = 0; j < CT; ++j) acc[i][j] = zero;

    const int sr = tid >> 3;
    const int sc_ = tid & 7;
    const int g = sc_ ^ (sr & 7);

    for (int k0 = 0; k0 < K; k0 += 64) {
        __syncthreads();
#pragma unroll
        for (int i = 0; i < 4; ++i) {
            int r = i * 32 + sr;
            load_lds16(A + (size_t)(tm + r) * K + k0 + g * 8, &sA[(i * 32 + w * 8) * 64]);
        }
#pragma unroll
        for (int i = 0; i < NT / 32; ++i) {
            int r = i * 32 + sr;
            load_lds16(B + (size_t)(tn + r) * K + k0 + g * 8, &sB[(i * 32 + w * 8) * 64]);
        }
        __syncthreads();
#pragma unroll
        for (int kk = 0; kk < 2; ++kk) {
            bf16x8 af[4], bfr[CT];
            const int s = (kk * 4 + q) ^ (m & 7);
#pragma unroll
            for (int rt = 0; rt < 4; ++rt) {
                int R = wr * 64 + rt * 16 + m;
                af[rt] = *(const bf16x8*)&sA[R * 64 + s * 8];
            }
#pragma unroll
            for (int ct = 0; ct < CT; ++ct) {
                int R = wc * (NT / 2) + ct * 16 + m;
                bfr[ct] = *(const bf16x8*)&sB[R * 64 + s * 8];
            }
#pragma unroll
            for (int rt = 0; rt < 4; ++rt)
#pragma unroll
                for (int ct = 0; ct < CT; ++ct)
                    acc[rt][ct] = __builtin_amdgcn_mfma_f32_16x16x32_bf16(
                        af[rt], bfr[ct], acc[rt][ct], 0, 0, 0);
        }
    }

    const int sect = tn >> 10;  // MODE 3 only; block-uniform (128 | 1024)
#pragma unroll
    for (int ct = 0; ct < CT; ++ct) {
        int col = tn + wc * (NT / 2) + ct * 16 + m;
        float bv = bf2f(bias[col]);
#pragma unroll
        for (int rt = 0; rt < 4; ++rt) {
            int rowb = tm + wr * 64 + rt * 16 + q * 4;
#pragma unroll
            for (int rg = 0; rg < 4; ++rg) {
                int t = rowb + rg;
                float v = acc[rt][ct][rg] + bv;
                if (relu) v = fmaxf(v, 0.f);
                size_t off;
                if (MODE == 0) {
                    off = (size_t)t * N + col;
                } else {
                    int c = col & 1023;
                    int bh = (t & 3) * 16 + (c >> 6);
                    if (sect == 0) {
                        off = (size_t)bh * 131072 + (t >> 2) * 64 + (c & 63);
                        v *= 0.18033688f;  // 1/(8*ln2)
                    } else if (sect == 1) {
                        off = 8388608ull + (size_t)bh * 131072 + (t >> 2) * 64 + (c & 63);
                    } else {
                        off = 16777216ull + (size_t)bh * 131072 + (size_t)(c & 63) * 2048 + (t >> 2);
                    }
                }
                C[off] = f2bf(v);
            }
        }
    }
}

// ---------- flash attention ----------
// Row-sum l via ones-column MFMA (Lacc): C/D row mapping of Lacc == Oa, so
// l for Oa[nb][j] is Lacc[j] directly; deletes 32 VALU adds/iter + shuffle epi.
__global__ __launch_bounds__(256) void attn2(
    const uint16_t* __restrict__ Qh, const uint16_t* __restrict__ Kh,
    const uint16_t* __restrict__ Vt, uint16_t* __restrict__ CTX)
{
    __shared__ uint16_t sK[2][64 * 64];
    __shared__ uint16_t sV[2][64 * 64];

    const int tid = threadIdx.x;
    const int w = tid >> 6, ln = tid & 63;
    const int m5 = ln & 31, h5 = ln >> 5;
    const int bh = blockIdx.x, qt = blockIdx.y;
    const uint16_t* Qb = Qh + (size_t)bh * 131072;
    const uint16_t* Kb = Kh + (size_t)bh * 131072;
    const uint16_t* Vb = Vt + (size_t)bh * 131072;

    const int qrow = qt * 128 + w * 32 + m5;
    bf16x8 qf[4];
#pragma unroll
    for (int ks = 0; ks < 4; ++ks)
        qf[ks] = *(const bf16x8*)(Qb + (size_t)qrow * 64 + ks * 16 + h5 * 8);

    f32x16 Oa[2], Lacc;
#pragma unroll
    for (int nb = 0; nb < 2; ++nb)
#pragma unroll
        for (int i = 0; i < 16; ++i) Oa[nb][i] = 0.f;
#pragma unroll
    for (int i = 0; i < 16; ++i) Lacc[i] = 0.f;

    // all-ones bf16 B-fragment for the row-sum MFMA
    union { uint16_t u[8]; bf16x8 v; } one8;
#pragma unroll
    for (int i = 0; i < 8; ++i) one8.u[i] = 0x3F80;

    const int sr = tid >> 3;
    const int g = (tid & 7) ^ (sr & 7);

    {
        load_lds16(Kb + (size_t)sr * 64 + g * 8,            &sK[0][tid * 8]);
        load_lds16(Kb + (size_t)(sr + 32) * 64 + g * 8,     &sK[0][2048 + tid * 8]);
        load_lds16(Vb + (size_t)sr * 2048 + g * 8,          &sV[0][tid * 8]);
        load_lds16(Vb + (size_t)(sr + 32) * 2048 + g * 8,   &sV[0][2048 + tid * 8]);
    }

    for (int c = 0; c < 32; ++c) {
        const int cur = c & 1;
        __syncthreads();
        if (c + 1 < 32) {
            const int nc = c + 1;
            uint16_t* kd = &sK[cur ^ 1][0];
            uint16_t* vd = &sV[cur ^ 1][0];
            load_lds16(Kb + (size_t)(nc * 64 + sr) * 64 + g * 8,        kd + tid * 8);
            load_lds16(Kb + (size_t)(nc * 64 + sr + 32) * 64 + g * 8,   kd + 2048 + tid * 8);
            load_lds16(Vb + (size_t)sr * 2048 + nc * 64 + g * 8,        vd + tid * 8);
            load_lds16(Vb + (size_t)(sr + 32) * 2048 + nc * 64 + g * 8, vd + 2048 + tid * 8);
        }

        bf16x8 pf[4];
#pragma unroll
        for (int kb = 0; kb < 2; ++kb) {
            f32x16 acc;
#pragma unroll
            for (int i = 0; i < 16; ++i) acc[i] = 0.f;
#pragma unroll
            for (int ks = 0; ks < 4; ++ks) {
                int row = kb * 32 + m5;
                int ph = (2 * ks + h5) ^ (m5 & 7);
                bf16x8 kf = *(const bf16x8*)&sK[cur][row * 64 + ph * 8];
                acc = __builtin_amdgcn_mfma_f32_32x32x16_bf16(kf, qf[ks], acc, 0, 0, 0);
            }
#pragma unroll
            for (int ksl = 0; ksl < 2; ++ksl) {
                float p0 = exp2r(acc[8 * ksl + 0]);
                float p1 = exp2r(acc[8 * ksl + 1]);
                float p2 = exp2r(acc[8 * ksl + 2]);
                float p3 = exp2r(acc[8 * ksl + 3]);
                float p4 = exp2r(acc[8 * ksl + 4]);
                float p5 = exp2r(acc[8 * ksl + 5]);
                float p6 = exp2r(acc[8 * ksl + 6]);
                float p7 = exp2r(acc[8 * ksl + 7]);
                uint32_t x0 = pack2t(p0, p1);
                uint32_t x1 = pack2t(p2, p3);
                uint32_t y0 = pack2t(p4, p5);
                uint32_t y1 = pack2t(p6, p7);
                plane32_swap(x0, y0);
                plane32_swap(x1, y1);
                union { uint32_t u[4]; bf16x8 v; } pu;
                pu.u[0] = x0; pu.u[1] = x1; pu.u[2] = y0; pu.u[3] = y1;
                pf[kb * 2 + ksl] = pu.v;
            }
        }

#pragma unroll
        for (int ks = 0; ks < 4; ++ks) {
            Lacc = __builtin_amdgcn_mfma_f32_32x32x16_bf16(pf[ks], one8.v, Lacc, 0, 0, 0);
#pragma unroll
            for (int nb = 0; nb < 2; ++nb) {
                int vrow = nb * 32 + m5;
                int ph = (2 * ks + h5) ^ (m5 & 7);
                bf16x8 vf = *(const bf16x8*)&sV[cur][vrow * 64 + ph * 8];
                Oa[nb] = __builtin_amdgcn_mfma_f32_32x32x16_bf16(pf[ks], vf, Oa[nb], 0, 0, 0);
            }
        }
    }

    float Li[16];
#pragma unroll
    for (int j = 0; j < 16; ++j) Li[j] = 1.f / Lacc[j];

    const int b_ = bh >> 4, h_ = bh & 15;
#pragma unroll
    for (int nb = 0; nb < 2; ++nb)
#pragma unroll
        for (int a = 0; a < 4; ++a)
#pragma unroll
            for (int r = 0; r < 4; ++r) {
                int qr = r + 8 * a + 4 * h5;
                int s = qt * 128 + w * 32 + qr;
                int col = h_ * 64 + nb * 32 + m5;
                CTX[(size_t)(s * 4 + b_) * 1024 + col] = f2bf(Oa[nb][4 * a + r] * Li[4 * a + r]);
            }
}

// ---------- fused residual + LayerNorm ----------
template<bool RES_F32, bool OUT_F32>
__global__ __launch_bounds__(256) void ln_resid(
    const uint16_t* __restrict__ Y, const void* __restrict__ Xp,
    const float* __restrict__ G, const float* __restrict__ Bv,
    void* __restrict__ Op)
{
    const int row = blockIdx.x, tid = threadIdx.x;
    const size_t base = (size_t)row * 1024 + tid * 4;
    ushort4 yv = *(const ushort4*)(Y + base);
    float x0, x1, x2, x3;
    if (RES_F32) {
        float4 xv = *(const float4*)((const float*)Xp + base);
        x0 = xv.x; x1 = xv.y; x2 = xv.z; x3 = xv.w;
    } else {
        ushort4 xv = *(const ushort4*)((const uint16_t*)Xp + base);
        x0 = bf2f(xv.x); x1 = bf2f(xv.y); x2 = bf2f(xv.z); x3 = bf2f(xv.w);
    }
    float v0 = bf2f(yv.x) + x0;
    float v1 = bf2f(yv.y) + x1;
    float v2 = bf2f(yv.z) + x2;
    float v3 = bf2f(yv.w) + x3;
    float s = v0 + v1 + v2 + v3;
    float ss = v0 * v0 + v1 * v1 + v2 * v2 + v3 * v3;
#pragma unroll
    for (int off = 32; off > 0; off >>= 1) {
        s += __shfl_down(s, off);
        ss += __shfl_down(ss, off);
    }
    __shared__ float rs[4], rss[4];
    if ((tid & 63) == 0) { rs[tid >> 6] = s; rss[tid >> 6] = ss; }
    __syncthreads();
    float S = rs[0] + rs[1] + rs[2] + rs[3];
    float SS = rss[0] + rss[1] + rss[2] + rss[3];
    const float invn = 1.f / 1024.f;
    float mu = S * invn;
    float var = SS * invn - mu * mu;
    float rstd = rsqrtf(var + 1e-5f);
    float4 gv = *(const float4*)(G + tid * 4);
    float4 bv = *(const float4*)(Bv + tid * 4);
    float o0 = (v0 - mu) * rstd * gv.x + bv.x;
    float o1 = (v1 - mu) * rstd * gv.y + bv.y;
    float o2 = (v2 - mu) * rstd * gv.z + bv.z;
    float o3 = (v3 - mu) * rstd * gv.w + bv.w;
    if (OUT_F32) {
        float4 o = {o0, o1, o2, o3};
        *(float4*)((float*)Op + base) = o;
    } else {
        ushort4 o;
        o.x = f2bf(o0); o.y = f2bf(o1); o.z = f2bf(o2); o.w = f2bf(o3);
        *(ushort4*)((uint16_t*)Op + base) = o;
    }
}

// ---------- launch ----------
extern "C" void kernel_launch(void* const* d_in, const int* in_sizes, int n_in,
                              void* d_out, int out_size, void* d_ws, size_t ws_size,
                              hipStream_t stream)
{
    const float* X    = (const float*)d_in[0];
    const float* WQw  = (const float*)d_in[1];
    const float* WQb  = (const float*)d_in[2];
    const float* WKw  = (const float*)d_in[3];
    const float* WKb  = (const float*)d_in[4];
    const float* WVw  = (const float*)d_in[5];
    const float* WVb  = (const float*)d_in[6];
    const float* WOw  = (const float*)d_in[7];
    const float* WOb  = (const float*)d_in[8];
    const float* ln1g = (const float*)d_in[9];
    const float* ln1b = (const float*)d_in[10];
    const float* W1   = (const float*)d_in[11];
    const float* b1   = (const float*)d_in[12];
    const float* W2   = (const float*)d_in[13];
    const float* b2   = (const float*)d_in[14];
    const float* ln2g = (const float*)d_in[15];
    const float* ln2b = (const float*)d_in[16];

    uint16_t* ws = (uint16_t*)d_ws;
    const size_t E = 8192ull * 1024ull;
    const size_t MW = 1048576ull;
    uint16_t* Xb   = ws;
    uint16_t* qh   = ws + E;
    uint16_t* kh   = ws + 2 * E;
    uint16_t* vt   = ws + 3 * E;
    uint16_t* ctx  = ws + 4 * E;
    uint16_t* y    = qh;
    uint16_t* x1   = kh;
    uint16_t* m2   = vt;
    uint16_t* hbuf = ws + 5 * E;
    uint16_t* wq   = ws + 9 * E;
    uint16_t* wo   = wq + 3 * MW;
    uint16_t* w1   = wo + MW;
    uint16_t* w2   = w1 + 4 * MW;
    uint16_t* bq   = w2 + 4 * MW;
    uint16_t* bo   = bq + 3072;
    uint16_t* bb1  = bo + 1024;
    uint16_t* bb2  = bb1 + 4096;

    cvt_all<<<dim3(20481), dim3(256), 0, stream>>>(
        X, WQw, WKw, WVw, WOw, W1, W2, WQb, WKb, WVb, WOb, b1, b2,
        Xb, wq, bq);

    dim3 blk(256);
    // QKV: revert to gemm_bt<3,128> (round-2 path; gemm8 measured 97.3 us,
    // this was <96.6 and FLOP-scales to ~73 us at W1's measured rate)
    gemm_bt<3, 128, 0><<<dim3(24, 64), blk, 0, stream>>>(Xb,   wq, bq,  qh,   1024, 3072, 0, 0);
    attn2<<<dim3(64, 16), blk, 0, stream>>>(qh, kh, vt, ctx);
    gemm_bt<0, 64, 0><<<dim3(16, 64),  blk, 0, stream>>>(ctx,  wo, bo,  y,    1024, 1024, 0, 0);
    ln_resid<true, false><<<dim3(8192), blk, 0, stream>>>(y, X, ln1g, ln1b, x1);
    // W1: gemm_bt 128x128 (measured 97.5 best)
    gemm_bt<0, 128, 0><<<dim3(32, 64), blk, 0, stream>>>(x1,   w1, bb1, hbuf, 1024, 4096, 0, 1);
    // W2: M-major XCD swizzle (1024 blocks, nbx=16) — A-slice per XCD 8MB,
    // A fetched ~once vs full 64MB restream per XCD with the naive mapping
    gemm_bt<0, 64, 1><<<dim3(1024), blk, 0, stream>>>(hbuf, w2, bb2, m2,   4096, 1024, 16, 0);
    ln_resid<false, true><<<dim3(8192), blk, 0, stream>>>(m2, x1, ln2g, ln2b, d_out);
}

// Round 9
// 514.167 us; speedup vs baseline: 1.1145x; 1.0878x over previous
//
#include <hip/hip_runtime.h>
#include <stdint.h>

// ---------- types & helpers ----------
typedef short bf16x8 __attribute__((ext_vector_type(8)));
typedef float f32x4 __attribute__((ext_vector_type(4)));
typedef float f32x16 __attribute__((ext_vector_type(16)));

__device__ __forceinline__ float bf2f(uint16_t u) {
    union { uint32_t i; float f; } c; c.i = ((uint32_t)u) << 16; return c.f;
}
__device__ __forceinline__ uint16_t f2bf(float f) {
    union { float f; uint32_t i; } c; c.f = f;
    uint32_t x = c.i;
    return (uint16_t)((x + 0x7fffu + ((x >> 16) & 1u)) >> 16);  // RNE
}
// truncating pack: (bf16(hi)<<16)|bf16(lo) — OK for all-positive P
__device__ __forceinline__ uint32_t pack2t(float lo, float hi) {
    union { float f; uint32_t u; } a, b;
    a.f = lo; b.f = hi;
    return __builtin_amdgcn_perm(b.u, a.u, 0x07060302u);
}

// raw v_exp_f32 (2^x) — skips OCML denormal-range fixup; scores are bounded
__device__ __forceinline__ float exp2r(float x) {
#if __has_builtin(__builtin_amdgcn_exp2f)
    return __builtin_amdgcn_exp2f(x);
#else
    return exp2f(x);
#endif
}

// v_permlane32_swap_b32:
// post: a[l<32]=a_old[l], a[l>=32]=b_old[l-32];  b[l<32]=a_old[l+32], b[l>=32]=b_old[l]
__device__ __forceinline__ void plane32_swap(uint32_t& a, uint32_t& b) {
#if __has_builtin(__builtin_amdgcn_permlane32_swap)
    typedef unsigned int u32x2 __attribute__((ext_vector_type(2)));
    u32x2 r = __builtin_amdgcn_permlane32_swap(a, b, false, false);
    a = r[0]; b = r[1];
#else
    asm volatile("v_permlane32_swap_b32 %0, %1" : "+v"(a), "+v"(b));
#endif
}

// async global->LDS, 16B per lane; LDS dest = wave-uniform base + lane*16
__device__ __forceinline__ void load_lds16(const void* g, void* lds) {
    using gp_t = const __attribute__((address_space(1))) uint32_t*;
    using lp_t = __attribute__((address_space(3))) uint32_t*;
    __builtin_amdgcn_global_load_lds(
        reinterpret_cast<gp_t>(reinterpret_cast<uintptr_t>(g)),
        reinterpret_cast<lp_t>((uint32_t)reinterpret_cast<uintptr_t>(lds)),
        16, 0, 0);
}

// ---------- single-launch fp32 -> bf16 convert for all inputs ----------
__global__ __launch_bounds__(256) void cvt_all(
    const float* __restrict__ X,
    const float* __restrict__ wqf, const float* __restrict__ wkf,
    const float* __restrict__ wvf, const float* __restrict__ wof,
    const float* __restrict__ w1f, const float* __restrict__ w2f,
    const float* __restrict__ bqf, const float* __restrict__ bkf,
    const float* __restrict__ bvf, const float* __restrict__ bof,
    const float* __restrict__ b1f, const float* __restrict__ b2f,
    uint16_t* __restrict__ Xb, uint16_t* __restrict__ wd, uint16_t* __restrict__ bd)
{
    const int b = blockIdx.x, tid = threadIdx.x;
    const size_t M = 1048576ull;
    const float* s; uint16_t* d; size_t i, off;
    if (b < 8192) {
        i = ((size_t)b * 256 + tid) * 4;
        s = X; off = i; d = Xb;
    } else if (b < 20480) {
        i = ((size_t)(b - 8192) * 256 + tid) * 4;
        d = wd;
        if (i < M)           { s = wqf; off = i; }
        else if (i < 2 * M)  { s = wkf; off = i - M; }
        else if (i < 3 * M)  { s = wvf; off = i - 2 * M; }
        else if (i < 4 * M)  { s = wof; off = i - 3 * M; }
        else if (i < 8 * M)  { s = w1f; off = i - 4 * M; }
        else                 { s = w2f; off = i - 8 * M; }
    } else {
        int j = tid * 4;
        d = bd;
        for (int p = 0; p < 9; ++p, j += 1024) {
            const float* sb; int ob;
            if (j < 1024)      { sb = bqf; ob = j; }
            else if (j < 2048) { sb = bkf; ob = j - 1024; }
            else if (j < 3072) { sb = bvf; ob = j - 2048; }
            else if (j < 4096) { sb = bof; ob = j - 3072; }
            else if (j < 8192) { sb = b1f; ob = j - 4096; }
            else               { sb = b2f; ob = j - 8192; }
            float4 x = *(const float4*)(sb + ob);
            ushort4 u;
            u.x = f2bf(x.x); u.y = f2bf(x.y); u.z = f2bf(x.z); u.w = f2bf(x.w);
            *(ushort4*)(d + j) = u;
        }
        return;
    }
    float4 x = *(const float4*)(s + off);
    ushort4 u;
    u.x = f2bf(x.x); u.y = f2bf(x.y); u.z = f2bf(x.z); u.w = f2bf(x.w);
    *(ushort4*)(d + i) = u;
}

// ---------- generic bf16 GEMM: C = A[M,K] @ B[N,K]^T + bias (opt relu) ----------
// 128xNT tile, BK=64, 256 threads (4 waves, 2x2). Multi-block/CU overlap is the
// pipelining mechanism (m114) — measured best structure in this pipeline.
// MODE 0: C[t*N+col] linear.  MODE 3: fused QKV scatter (N=3072, NT=128).
// SWZ 1: 1-D grid, M-major XCD mapping — XCD = lin&7 owns contiguous M-tiles,
//        so per-XCD A-slice is small and A-panels stay L2-resident
//        (fixes the A-restream pathology measured on W2-NT128: 266MB FETCH).
template<int MODE, int NT, int SWZ>
__global__ __launch_bounds__(256) void gemm_bt(
    const uint16_t* __restrict__ A, const uint16_t* __restrict__ B,
    const uint16_t* __restrict__ bias, uint16_t* __restrict__ C,
    int K, int N, int nbx, int relu)
{
    const int CT = NT / 32;
    __shared__ uint16_t sA[128 * 64];
    __shared__ uint16_t sB[NT * 64];
    const int tid = threadIdx.x;
    const int w = tid >> 6, ln = tid & 63;
    const int m = ln & 15, q = ln >> 4;
    const int wr = w >> 1, wc = w & 1;

    int bx, by;
    if (SWZ) {
        const int lin = blockIdx.x;
        const int xcd = lin & 7, idx = lin >> 3;
        const int per = (gridDim.x >> 3) / nbx;   // M-groups per XCD
        by = xcd * per + idx / nbx;
        bx = idx % nbx;
    } else {
        bx = blockIdx.x; by = blockIdx.y;
    }
    const int tm = by * 128, tn = bx * NT;

    f32x4 zero = {0.f, 0.f, 0.f, 0.f};
    f32x4 acc[4][CT];
#pragma unroll
    for (int i = 0; i < 4; ++i)
#pragma unroll
        for (int j = 0; j < CT; ++j) acc[i][j] = zero;

    const int sr = tid >> 3;
    const int sc_ = tid & 7;
    const int g = sc_ ^ (sr & 7);

    for (int k0 = 0; k0 < K; k0 += 64) {
        __syncthreads();
#pragma unroll
        for (int i = 0; i < 4; ++i) {
            int r = i * 32 + sr;
            load_lds16(A + (size_t)(tm + r) * K + k0 + g * 8, &sA[(i * 32 + w * 8) * 64]);
        }
#pragma unroll
        for (int i = 0; i < NT / 32; ++i) {
            int r = i * 32 + sr;
            load_lds16(B + (size_t)(tn + r) * K + k0 + g * 8, &sB[(i * 32 + w * 8) * 64]);
        }
        __syncthreads();
#pragma unroll
        for (int kk = 0; kk < 2; ++kk) {
            bf16x8 af[4], bfr[CT];
            const int s = (kk * 4 + q) ^ (m & 7);
#pragma unroll
            for (int rt = 0; rt < 4; ++rt) {
                int R = wr * 64 + rt * 16 + m;
                af[rt] = *(const bf16x8*)&sA[R * 64 + s * 8];
            }
#pragma unroll
            for (int ct = 0; ct < CT; ++ct) {
                int R = wc * (NT / 2) + ct * 16 + m;
                bfr[ct] = *(const bf16x8*)&sB[R * 64 + s * 8];
            }
#pragma unroll
            for (int rt = 0; rt < 4; ++rt)
#pragma unroll
                for (int ct = 0; ct < CT; ++ct)
                    acc[rt][ct] = __builtin_amdgcn_mfma_f32_16x16x32_bf16(
                        af[rt], bfr[ct], acc[rt][ct], 0, 0, 0);
        }
    }

    const int sect = tn >> 10;  // MODE 3 only; block-uniform (128 | 1024)
#pragma unroll
    for (int ct = 0; ct < CT; ++ct) {
        int col = tn + wc * (NT / 2) + ct * 16 + m;
        float bv = bf2f(bias[col]);
#pragma unroll
        for (int rt = 0; rt < 4; ++rt) {
            int rowb = tm + wr * 64 + rt * 16 + q * 4;
#pragma unroll
            for (int rg = 0; rg < 4; ++rg) {
                int t = rowb + rg;
                float v = acc[rt][ct][rg] + bv;
                if (relu) v = fmaxf(v, 0.f);
                size_t off;
                if (MODE == 0) {
                    off = (size_t)t * N + col;
                } else {
                    int c = col & 1023;
                    int bh = (t & 3) * 16 + (c >> 6);
                    if (sect == 0) {
                        off = (size_t)bh * 131072 + (t >> 2) * 64 + (c & 63);
                        v *= 0.18033688f;  // 1/(8*ln2)
                    } else if (sect == 1) {
                        off = 8388608ull + (size_t)bh * 131072 + (t >> 2) * 64 + (c & 63);
                    } else {
                        off = 16777216ull + (size_t)bh * 131072 + (size_t)(c & 63) * 2048 + (t >> 2);
                    }
                }
                C[off] = f2bf(v);
            }
        }
    }
}

// ---------- flash attention ----------
// Row-sum l via ones-column MFMA (Lacc): C/D row mapping of Lacc == Oa, so
// l for Oa[nb][j] is Lacc[j] directly; deletes 32 VALU adds/iter + shuffle epi.
__global__ __launch_bounds__(256) void attn2(
    const uint16_t* __restrict__ Qh, const uint16_t* __restrict__ Kh,
    const uint16_t* __restrict__ Vt, uint16_t* __restrict__ CTX)
{
    __shared__ uint16_t sK[2][64 * 64];
    __shared__ uint16_t sV[2][64 * 64];

    const int tid = threadIdx.x;
    const int w = tid >> 6, ln = tid & 63;
    const int m5 = ln & 31, h5 = ln >> 5;
    const int bh = blockIdx.x, qt = blockIdx.y;
    const uint16_t* Qb = Qh + (size_t)bh * 131072;
    const uint16_t* Kb = Kh + (size_t)bh * 131072;
    const uint16_t* Vb = Vt + (size_t)bh * 131072;

    const int qrow = qt * 128 + w * 32 + m5;
    bf16x8 qf[4];
#pragma unroll
    for (int ks = 0; ks < 4; ++ks)
        qf[ks] = *(const bf16x8*)(Qb + (size_t)qrow * 64 + ks * 16 + h5 * 8);

    f32x16 Oa[2], Lacc;
#pragma unroll
    for (int nb = 0; nb < 2; ++nb)
#pragma unroll
        for (int i = 0; i < 16; ++i) Oa[nb][i] = 0.f;
#pragma unroll
    for (int i = 0; i < 16; ++i) Lacc[i] = 0.f;

    // all-ones bf16 B-fragment for the row-sum MFMA
    union { uint16_t u[8]; bf16x8 v; } one8;
#pragma unroll
    for (int i = 0; i < 8; ++i) one8.u[i] = 0x3F80;

    const int sr = tid >> 3;
    const int g = (tid & 7) ^ (sr & 7);

    {
        load_lds16(Kb + (size_t)sr * 64 + g * 8,            &sK[0][tid * 8]);
        load_lds16(Kb + (size_t)(sr + 32) * 64 + g * 8,     &sK[0][2048 + tid * 8]);
        load_lds16(Vb + (size_t)sr * 2048 + g * 8,          &sV[0][tid * 8]);
        load_lds16(Vb + (size_t)(sr + 32) * 2048 + g * 8,   &sV[0][2048 + tid * 8]);
    }

    for (int c = 0; c < 32; ++c) {
        const int cur = c & 1;
        __syncthreads();
        if (c + 1 < 32) {
            const int nc = c + 1;
            uint16_t* kd = &sK[cur ^ 1][0];
            uint16_t* vd = &sV[cur ^ 1][0];
            load_lds16(Kb + (size_t)(nc * 64 + sr) * 64 + g * 8,        kd + tid * 8);
            load_lds16(Kb + (size_t)(nc * 64 + sr + 32) * 64 + g * 8,   kd + 2048 + tid * 8);
            load_lds16(Vb + (size_t)sr * 2048 + nc * 64 + g * 8,        vd + tid * 8);
            load_lds16(Vb + (size_t)(sr + 32) * 2048 + nc * 64 + g * 8, vd + 2048 + tid * 8);
        }

        bf16x8 pf[4];
#pragma unroll
        for (int kb = 0; kb < 2; ++kb) {
            f32x16 acc;
#pragma unroll
            for (int i = 0; i < 16; ++i) acc[i] = 0.f;
#pragma unroll
            for (int ks = 0; ks < 4; ++ks) {
                int row = kb * 32 + m5;
                int ph = (2 * ks + h5) ^ (m5 & 7);
                bf16x8 kf = *(const bf16x8*)&sK[cur][row * 64 + ph * 8];
                acc = __builtin_amdgcn_mfma_f32_32x32x16_bf16(kf, qf[ks], acc, 0, 0, 0);
            }
#pragma unroll
            for (int ksl = 0; ksl < 2; ++ksl) {
                float p0 = exp2r(acc[8 * ksl + 0]);
                float p1 = exp2r(acc[8 * ksl + 1]);
                float p2 = exp2r(acc[8 * ksl + 2]);
                float p3 = exp2r(acc[8 * ksl + 3]);
                float p4 = exp2r(acc[8 * ksl + 4]);
                float p5 = exp2r(acc[8 * ksl + 5]);
                float p6 = exp2r(acc[8 * ksl + 6]);
                float p7 = exp2r(acc[8 * ksl + 7]);
                uint32_t x0 = pack2t(p0, p1);
                uint32_t x1 = pack2t(p2, p3);
                uint32_t y0 = pack2t(p4, p5);
                uint32_t y1 = pack2t(p6, p7);
                plane32_swap(x0, y0);
                plane32_swap(x1, y1);
                union { uint32_t u[4]; bf16x8 v; } pu;
                pu.u[0] = x0; pu.u[1] = x1; pu.u[2] = y0; pu.u[3] = y1;
                pf[kb * 2 + ksl] = pu.v;
            }
        }

#pragma unroll
        for (int ks = 0; ks < 4; ++ks) {
            Lacc = __builtin_amdgcn_mfma_f32_32x32x16_bf16(pf[ks], one8.v, Lacc, 0, 0, 0);
#pragma unroll
            for (int nb = 0; nb < 2; ++nb) {
                int vrow = nb * 32 + m5;
                int ph = (2 * ks + h5) ^ (m5 & 7);
                bf16x8 vf = *(const bf16x8*)&sV[cur][vrow * 64 + ph * 8];
                Oa[nb] = __builtin_amdgcn_mfma_f32_32x32x16_bf16(pf[ks], vf, Oa[nb], 0, 0, 0);
            }
        }
    }

    float Li[16];
#pragma unroll
    for (int j = 0; j < 16; ++j) Li[j] = 1.f / Lacc[j];

    const int b_ = bh >> 4, h_ = bh & 15;
#pragma unroll
    for (int nb = 0; nb < 2; ++nb)
#pragma unroll
        for (int a = 0; a < 4; ++a)
#pragma unroll
            for (int r = 0; r < 4; ++r) {
                int qr = r + 8 * a + 4 * h5;
                int s = qt * 128 + w * 32 + qr;
                int col = h_ * 64 + nb * 32 + m5;
                CTX[(size_t)(s * 4 + b_) * 1024 + col] = f2bf(Oa[nb][4 * a + r] * Li[4 * a + r]);
            }
}

// ---------- fused residual + LayerNorm ----------
template<bool RES_F32, bool OUT_F32>
__global__ __launch_bounds__(256) void ln_resid(
    const uint16_t* __restrict__ Y, const void* __restrict__ Xp,
    const float* __restrict__ G, const float* __restrict__ Bv,
    void* __restrict__ Op)
{
    const int row = blockIdx.x, tid = threadIdx.x;
    const size_t base = (size_t)row * 1024 + tid * 4;
    ushort4 yv = *(const ushort4*)(Y + base);
    float x0, x1, x2, x3;
    if (RES_F32) {
        float4 xv = *(const float4*)((const float*)Xp + base);
        x0 = xv.x; x1 = xv.y; x2 = xv.z; x3 = xv.w;
    } else {
        ushort4 xv = *(const ushort4*)((const uint16_t*)Xp + base);
        x0 = bf2f(xv.x); x1 = bf2f(xv.y); x2 = bf2f(xv.z); x3 = bf2f(xv.w);
    }
    float v0 = bf2f(yv.x) + x0;
    float v1 = bf2f(yv.y) + x1;
    float v2 = bf2f(yv.z) + x2;
    float v3 = bf2f(yv.w) + x3;
    float s = v0 + v1 + v2 + v3;
    float ss = v0 * v0 + v1 * v1 + v2 * v2 + v3 * v3;
#pragma unroll
    for (int off = 32; off > 0; off >>= 1) {
        s += __shfl_down(s, off);
        ss += __shfl_down(ss, off);
    }
    __shared__ float rs[4], rss[4];
    if ((tid & 63) == 0) { rs[tid >> 6] = s; rss[tid >> 6] = ss; }
    __syncthreads();
    float S = rs[0] + rs[1] + rs[2] + rs[3];
    float SS = rss[0] + rss[1] + rss[2] + rss[3];
    const float invn = 1.f / 1024.f;
    float mu = S * invn;
    float var = SS * invn - mu * mu;
    float rstd = rsqrtf(var + 1e-5f);
    float4 gv = *(const float4*)(G + tid * 4);
    float4 bv = *(const float4*)(Bv + tid * 4);
    float o0 = (v0 - mu) * rstd * gv.x + bv.x;
    float o1 = (v1 - mu) * rstd * gv.y + bv.y;
    float o2 = (v2 - mu) * rstd * gv.z + bv.z;
    float o3 = (v3 - mu) * rstd * gv.w + bv.w;
    if (OUT_F32) {
        float4 o = {o0, o1, o2, o3};
        *(float4*)((float*)Op + base) = o;
    } else {
        ushort4 o;
        o.x = f2bf(o0); o.y = f2bf(o1); o.z = f2bf(o2); o.w = f2bf(o3);
        *(ushort4*)((uint16_t*)Op + base) = o;
    }
}

// ---------- launch ----------
extern "C" void kernel_launch(void* const* d_in, const int* in_sizes, int n_in,
                              void* d_out, int out_size, void* d_ws, size_t ws_size,
                              hipStream_t stream)
{
    const float* X    = (const float*)d_in[0];
    const float* WQw  = (const float*)d_in[1];
    const float* WQb  = (const float*)d_in[2];
    const float* WKw  = (const float*)d_in[3];
    const float* WKb  = (const float*)d_in[4];
    const float* WVw  = (const float*)d_in[5];
    const float* WVb  = (const float*)d_in[6];
    const float* WOw  = (const float*)d_in[7];
    const float* WOb  = (const float*)d_in[8];
    const float* ln1g = (const float*)d_in[9];
    const float* ln1b = (const float*)d_in[10];
    const float* W1   = (const float*)d_in[11];
    const float* b1   = (const float*)d_in[12];
    const float* W2   = (const float*)d_in[13];
    const float* b2   = (const float*)d_in[14];
    const float* ln2g = (const float*)d_in[15];
    const float* ln2b = (const float*)d_in[16];

    uint16_t* ws = (uint16_t*)d_ws;
    const size_t E = 8192ull * 1024ull;
    const size_t MW = 1048576ull;
    uint16_t* Xb   = ws;
    uint16_t* qh   = ws + E;
    uint16_t* kh   = ws + 2 * E;
    uint16_t* vt   = ws + 3 * E;
    uint16_t* ctx  = ws + 4 * E;
    uint16_t* y    = qh;
    uint16_t* x1   = kh;
    uint16_t* m2   = vt;
    uint16_t* hbuf = ws + 5 * E;
    uint16_t* wq   = ws + 9 * E;
    uint16_t* wo   = wq + 3 * MW;
    uint16_t* w1   = wo + MW;
    uint16_t* w2   = w1 + 4 * MW;
    uint16_t* bq   = w2 + 4 * MW;
    uint16_t* bo   = bq + 3072;
    uint16_t* bb1  = bo + 1024;
    uint16_t* bb2  = bb1 + 4096;

    cvt_all<<<dim3(20481), dim3(256), 0, stream>>>(
        X, WQw, WKw, WVw, WOw, W1, W2, WQb, WKb, WVb, WOb, b1, b2,
        Xb, wq, bq);

    dim3 blk(256);
    // QKV: NT=128 + M-major XCD swizzle (1536 blocks, nbx=24; per-XCD A 2MB)
    gemm_bt<3, 128, 1><<<dim3(1536), blk, 0, stream>>>(Xb,   wq, bq,  qh,   1024, 3072, 24, 0);
    attn2<<<dim3(64, 16), blk, 0, stream>>>(qh, kh, vt, ctx);
    // wo: NT=64 -> NT=128 + swizzle (512 blocks, nbx=8; B 2MB L2-resident)
    gemm_bt<0, 128, 1><<<dim3(512), blk, 0, stream>>>(ctx,  wo, bo,  y,    1024, 1024, 8, 0);
    ln_resid<true, false><<<dim3(8192), blk, 0, stream>>>(y, X, ln1g, ln1b, x1);
    // W1: unchanged (measured 97.5-best)
    gemm_bt<0, 128, 0><<<dim3(32, 64), blk, 0, stream>>>(x1,   w1, bb1, hbuf, 1024, 4096, 0, 1);
    // W2: NT=128 + M-major swizzle — NT=128 intensity without the A-restream
    // pathology (round 6: 266MB FETCH with naive mapping)
    gemm_bt<0, 128, 1><<<dim3(512), blk, 0, stream>>>(hbuf, w2, bb2, m2,   4096, 1024, 8, 0);
    ln_resid<false, true><<<dim3(8192), blk, 0, stream>>>(m2, x1, ln2g, ln2b, d_out);
}